// Round 10
// baseline (5225.468 us; speedup 1.0000x reference)
//
#include <hip/hip_runtime.h>
#include <float.h>

#define N_PTS 16384
#define M_PTS 4096
#define K_NN  16
#define CIN   64
#define COUT  64

typedef float v2f __attribute__((ext_vector_type(2)));
typedef unsigned long long ull;

// Exact f32 rounding to match numpy/jax: ((dx*dx + dy*dy) + dz*dz), no fma contraction.
__device__ __forceinline__ float dist2_exact(float ax, float ay, float az,
                                             float bx, float by, float bz) {
    float dx = __fsub_rn(ax, bx);
    float dy = __fsub_rn(ay, by);
    float dz = __fsub_rn(az, bz);
    return __fadd_rn(__fadd_rn(__fmul_rn(dx, dx), __fmul_rn(dy, dy)), __fmul_rn(dz, dz));
}

// Packed f32 ops via inline asm (v2f codegen otherwise scalarizes — R6 evidence).
__device__ __forceinline__ v2f pk_add(v2f a, v2f b) {
    v2f d; asm("v_pk_add_f32 %0, %1, %2" : "=v"(d) : "v"(a), "v"(b)); return d;
}
__device__ __forceinline__ v2f pk_mul(v2f a, v2f b) {
    v2f d; asm("v_pk_mul_f32 %0, %1, %2" : "=v"(d) : "v"(a), "v"(b)); return d;
}

// ---- DPP wave-64 reduction step for packed u64 keys (idempotent max) ----
template <int CTRL>
__device__ __forceinline__ ull dpp_u64max_step(ull x) {
    int lo = (int)(unsigned)x;
    int hi = (int)(unsigned)(x >> 32);
    unsigned olo = (unsigned)__builtin_amdgcn_update_dpp(lo, lo, CTRL, 0xf, 0xf, false);
    unsigned ohi = (unsigned)__builtin_amdgcn_update_dpp(hi, hi, CTRL, 0xf, 0xf, false);
    ull o = ((ull)ohi << 32) | (ull)olo;
    return o > x ? o : x;
}
__device__ __forceinline__ ull umax64(ull a, ull b) { return a > b ? a : b; }

// Morton bit-spread: 10 bits -> every 3rd bit.
__device__ __forceinline__ unsigned part1by2(unsigned v) {
    v &= 0x3ffu;
    v = (v | (v << 16)) & 0x030000FFu;
    v = (v | (v << 8))  & 0x0300F00Fu;
    v = (v | (v << 4))  & 0x030C30C3u;
    v = (v | (v << 2))  & 0x09249249u;
    return v;
}

// Compile-time-indexed 8-way select (uniform _sh -> cndmask tree, no scratch).
#define SEL8(arr)                                                                 \
    ((_sh & 4) ? ((_sh & 2) ? ((_sh & 1) ? arr[7] : arr[6])                       \
                            : ((_sh & 1) ? arr[5] : arr[4]))                      \
               : ((_sh & 2) ? ((_sh & 1) ? arr[3] : arr[2])                       \
                            : ((_sh & 1) ? arr[1] : arr[0])))

// Per-wave record extraction (R21): key = d2_bits<<32 | ((orig^0x3fff)<<14 | sortpos).
// u64-max == (argmax d2, tie-break min orig) — bit-identical winner selection to
// R1 (orig is unique and fits 14 bits, so sortpos never decides). sortpos encodes
// the owning thread, so NO ballot/ctz: candidate z comes from the owner lane's zp
// regs ((klo>>4)&63 within this wave) via uniform cndmask tree + one readlane.
#define EXTRACT_RECORD()                                                          \
    {                                                                             \
        ull _r = bk;                                                              \
        _r = dpp_u64max_step<0x111>(_r);                                          \
        _r = dpp_u64max_step<0x112>(_r);                                          \
        _r = dpp_u64max_step<0x114>(_r);                                          \
        _r = dpp_u64max_step<0x118>(_r);                                          \
        _r = dpp_u64max_step<0x142>(_r);                                          \
        _r = dpp_u64max_step<0x143>(_r);                                          \
        my_klo = (unsigned)__builtin_amdgcn_readlane((int)(unsigned)_r, 63);      \
        my_khi = (unsigned)__builtin_amdgcn_readlane((int)(unsigned)(_r >> 32), 63); \
        my_wval = __int_as_float((int)my_khi);                                    \
        const int _hl = (int)((my_klo >> 4) & 63u);    /* owner lane (own wave) */ \
        const int _slot = (int)(my_klo & 15u);                                    \
        const int _sh = _slot >> 1;                                              \
        v2f _za = SEL8(zp);                                                       \
        const float _zc = (_slot & 1) ? _za.y : _za.x;                            \
        my_qz = __int_as_float(__builtin_amdgcn_readlane(__float_as_int(_zc), _hl)); \
    }

// ---------------------------------------------------------------------------
// Kernel 1: furthest point sampling. R26 = R21 structure (one barrier/iter,
// sortpos-keyed records, z sidecar) with MORTON-order point layout + per-wave
// 3D AABB prune (replaces the x-slab prune). Sort order is only a permutation
// -> pick sequence bit-identical; the AABB test is the same conservative
// "no element can update" proof as the slab test, in 3D (R9 calibration:
// ~7 active waves with x-slabs; Morton cells should cut that to ~2-3, which
// is the remaining SIMD-issue contention term). kq recomputed in-loop from
// opk (saves 8 VGPRs; budget <64 — R2/R3: allocator caps at 64, spills past).
// ---------------------------------------------------------------------------
__global__ __launch_bounds__(1024) void fps_kernel(const float* __restrict__ p,
                                                   float* __restrict__ out) {
#pragma clang fp contract(off)
    const int t = threadIdx.x;
    const int lane = t & 63, wv = t >> 6;
    __shared__ char smem[147456];                      // keys[16384] then s_xy4[1024*9]
    __shared__ float s_pick[1024 * 3];                 // pick ring (12 KB)
    __shared__ ull s_rec[2][16];                       // bare u64 records
    __shared__ float s_recz[2][16];                    // winner-candidate z per wave

    ull* keys = (ull*)smem;
    float4* s_xy4 = (float4*)smem;                     // reuses keys region (144 KB)

    // ---- Phase A0: global min/max of x,y,z (for Morton normalization) ----
    float mnx = FLT_MAX, mny = FLT_MAX, mnz = FLT_MAX;
    float mxx = -FLT_MAX, mxy = -FLT_MAX, mxz = -FLT_MAX;
    for (int u = 0; u < 16; ++u) {
        const int j = u * 1024 + t;
        const float X = p[3 * j], Y = p[3 * j + 1], Z = p[3 * j + 2];
        mnx = fminf(mnx, X); mxx = fmaxf(mxx, X);
        mny = fminf(mny, Y); mxy = fmaxf(mxy, Y);
        mnz = fminf(mnz, Z); mxz = fmaxf(mxz, Z);
    }
#pragma unroll
    for (int off = 1; off < 64; off <<= 1) {
        mnx = fminf(mnx, __shfl_xor(mnx, off)); mxx = fmaxf(mxx, __shfl_xor(mxx, off));
        mny = fminf(mny, __shfl_xor(mny, off)); mxy = fmaxf(mxy, __shfl_xor(mxy, off));
        mnz = fminf(mnz, __shfl_xor(mnz, off)); mxz = fmaxf(mxz, __shfl_xor(mxz, off));
    }
    if (lane == 0) {                                   // s_pick as init scratch
        s_pick[wv * 6 + 0] = mnx; s_pick[wv * 6 + 1] = mxx;
        s_pick[wv * 6 + 2] = mny; s_pick[wv * 6 + 3] = mxy;
        s_pick[wv * 6 + 4] = mnz; s_pick[wv * 6 + 5] = mxz;
    }
    __syncthreads();
    for (int w = 0; w < 16; ++w) {
        mnx = fminf(mnx, s_pick[w * 6 + 0]); mxx = fmaxf(mxx, s_pick[w * 6 + 1]);
        mny = fminf(mny, s_pick[w * 6 + 2]); mxy = fmaxf(mxy, s_pick[w * 6 + 3]);
        mnz = fminf(mnz, s_pick[w * 6 + 4]); mxz = fmaxf(mxz, s_pick[w * 6 + 5]);
    }
    const float sx = 1024.0f / (mxx - mnx + 1e-7f);
    const float sy = 1024.0f / (mxy - mny + 1e-7f);
    const float sz = 1024.0f / (mxz - mnz + 1e-7f);

    // ---- Phase A: bitonic sort by Morton code (keys unique via idx bits) ----
    for (int u = 0; u < 16; ++u) {
        const int j = u * 1024 + t;
        const float X = p[3 * j], Y = p[3 * j + 1], Z = p[3 * j + 2];
        const unsigned ix = (unsigned)fminf((X - mnx) * sx, 1023.0f);
        const unsigned iy = (unsigned)fminf((Y - mny) * sy, 1023.0f);
        const unsigned iz = (unsigned)fminf((Z - mnz) * sz, 1023.0f);
        const unsigned mort = part1by2(ix) | (part1by2(iy) << 1) | (part1by2(iz) << 2);
        keys[j] = ((ull)mort << 14) | (unsigned)j;
    }
    __syncthreads();
    for (int k = 2; k <= N_PTS; k <<= 1) {
        for (int j = k >> 1; j > 0; j >>= 1) {
            for (int e = 0; e < 8; ++e) {
                const int c = e * 1024 + t;
                const int i1 = 2 * c - (c & (j - 1));
                const int i2 = i1 + j;
                const ull a = keys[i1], b = keys[i2];
                const bool up = ((i1 & k) == 0);
                if ((a > b) == up) { keys[i1] = b; keys[i2] = a; }
            }
            __syncthreads();
        }
    }

    // read own 16 sorted keys -> packed original indices (8 regs, 14-bit fields)
    unsigned opk[8];
#pragma unroll
    for (int u = 0; u < 8; ++u) {
        const ull a = keys[t * 16 + 2 * u];
        const ull b = keys[t * 16 + 2 * u + 1];
        opk[u] = ((unsigned)a & 0x3fffu) | (((unsigned)b & 0x3fffu) << 16);
    }
    __syncthreads();                                   // all key reads done before overwrite

    // ---- gather coords: LDS xy ({x0,x1,y0,y1}) + reg z/d2 + wave AABB ----
    v2f zp[8], d2[8];
    const float q0x = p[0], q0y = p[1], q0z = p[2];
    ull bk = 0;
    float bbmnx = FLT_MAX, bbmny = FLT_MAX, bbmnz = FLT_MAX;
    float bbmxx = -FLT_MAX, bbmxy = -FLT_MAX, bbmxz = -FLT_MAX;
#pragma unroll
    for (int u = 0; u < 8; ++u) {
        const int o0 = (int)(opk[u] & 0xffffu), o1 = (int)(opk[u] >> 16);
        const float x0 = p[3 * o0], y0 = p[3 * o0 + 1], z0 = p[3 * o0 + 2];
        const float x1 = p[3 * o1], y1 = p[3 * o1 + 1], z1 = p[3 * o1 + 2];
        s_xy4[t * 9 + u] = make_float4(x0, x1, y0, y1);
        zp[u] = (v2f){z0, z1};
        d2[u] = (v2f){dist2_exact(x0, y0, z0, q0x, q0y, q0z),
                      dist2_exact(x1, y1, z1, q0x, q0y, q0z)};
        const unsigned kq0 = (((unsigned)o0 ^ 0x3fffu) << 14) | (unsigned)(t * 16 + 2 * u);
        const unsigned kq1 = (((unsigned)o1 ^ 0x3fffu) << 14) | (unsigned)(t * 16 + 2 * u + 1);
        const ull ka = ((ull)__float_as_uint(d2[u].x) << 32) | (ull)kq0;
        const ull kb = ((ull)__float_as_uint(d2[u].y) << 32) | (ull)kq1;
        bk = umax64(bk, umax64(ka, kb));
        bbmnx = fminf(bbmnx, fminf(x0, x1)); bbmxx = fmaxf(bbmxx, fmaxf(x0, x1));
        bbmny = fminf(bbmny, fminf(y0, y1)); bbmxy = fmaxf(bbmxy, fmaxf(y0, y1));
        bbmnz = fminf(bbmnz, fminf(z0, z1)); bbmxz = fmaxf(bbmxz, fmaxf(z0, z1));
    }
#pragma unroll
    for (int off = 1; off < 64; off <<= 1) {           // wave AABB (uniform after)
        bbmnx = fminf(bbmnx, __shfl_xor(bbmnx, off)); bbmxx = fmaxf(bbmxx, __shfl_xor(bbmxx, off));
        bbmny = fminf(bbmny, __shfl_xor(bbmny, off)); bbmxy = fmaxf(bbmxy, __shfl_xor(bbmxy, off));
        bbmnz = fminf(bbmnz, __shfl_xor(bbmnz, off)); bbmxz = fmaxf(bbmxz, __shfl_xor(bbmxz, off));
    }

    float my_wval, my_qz;
    unsigned my_klo, my_khi;
    EXTRACT_RECORD();
    if (lane == 0) {
        s_rec[1][wv] = ((ull)my_khi << 32) | (ull)my_klo;
        s_recz[1][wv] = my_qz;
    }
    if (t == 0) { s_pick[0] = q0x; s_pick[1] = q0y; s_pick[2] = q0z; }

    for (int i = 1; i < M_PTS; ++i) {
        const int par = i & 1;
        __syncthreads();                               // the ONE barrier per iteration

        // ring flush: once per 512 iters, previous 512-block (other ring half)
        if ((i & 511) == 0) {
            const int b = (i - 512) & 1023;
            const int base3 = (i - 512) * 3;
            out[base3 + t] = s_pick[b * 3 + t];
            if (t < 512) out[base3 + 1024 + t] = s_pick[b * 3 + 1024 + t];
        }

        // global winner from the 16 records, then uniform broadcast coord fetch
        const int r = lane & 15;
        ull red = s_rec[par][r];
        red = dpp_u64max_step<0x111>(red);
        red = dpp_u64max_step<0x112>(red);
        red = dpp_u64max_step<0x114>(red);
        red = dpp_u64max_step<0x118>(red);
        const unsigned wlo = (unsigned)__builtin_amdgcn_readlane((int)(unsigned)red, 63);
        const unsigned sortpos = wlo & 0x3fffu;
        const int to = (int)(sortpos >> 4), slot = (int)(sortpos & 15u);
        const float qz = s_recz[par][sortpos >> 10];   // record idx = owning wave
        const float4 xy = s_xy4[to * 9 + (slot >> 1)]; // uniform addr -> broadcast
        const float qx = (slot & 1) ? xy.y : xy.x;
        const float qy = (slot & 1) ? xy.w : xy.z;
        if (t == 0) {
            const int s3 = (i & 1023) * 3;
            s_pick[s3] = qx; s_pick[s3 + 1] = qy; s_pick[s3 + 2] = qz;
        }

        // ---- wave-level AABB prune: skip update iff provably all no-ops.
        // dist(q, wave AABB)^2 > my_wval (wave max d2) => every element's new
        // candidate distance exceeds its current d2 => min() is a no-op.
        // +1e-5 absolute margin covers f32 rounding (conservative direction).
        const float ddx = fmaxf(0.0f, fmaxf(bbmnx - qx, qx - bbmxx));
        const float ddy = fmaxf(0.0f, fmaxf(bbmny - qy, qy - bbmxy));
        const float ddz = fmaxf(0.0f, fmaxf(bbmnz - qz, qz - bbmxz));
        const float lb2 = ddx * ddx + ddy * ddy + ddz * ddz;
        const bool active = (lb2 <= my_wval + 1e-5f);
        if (active) {
            const v2f nqx2 = (v2f){-qx, -qx};
            const v2f nqy2 = (v2f){-qy, -qy};
            const v2f nqz2 = (v2f){-qz, -qz};
            bk = 0;
#pragma unroll
            for (int u = 0; u < 8; ++u) {
                const float4 xyu = s_xy4[t * 9 + u];
                const v2f xp = (v2f){xyu.x, xyu.y};    // {x0,x1}
                const v2f yp = (v2f){xyu.z, xyu.w};    // {y0,y1}
                const v2f dx = pk_add(xp, nqx2);       // exact x - qx
                const v2f dy = pk_add(yp, nqy2);
                const v2f dz = pk_add(zp[u], nqz2);
                const v2f m1 = pk_mul(dx, dx);
                const v2f m2 = pk_mul(dy, dy);
                const v2f m3 = pk_mul(dz, dz);
                const v2f s = pk_add(pk_add(m1, m2), m3);  // ((x²+y²)+z²) exact order
                d2[u] = __builtin_elementwise_min(d2[u], s);
                const unsigned o0 = opk[u] & 0xffffu, o1 = opk[u] >> 16;
                const unsigned kq0 = ((o0 ^ 0x3fffu) << 14) | (unsigned)(t * 16 + 2 * u);
                const unsigned kq1 = ((o1 ^ 0x3fffu) << 14) | (unsigned)(t * 16 + 2 * u + 1);
                const ull ka = ((ull)__float_as_uint(d2[u].x) << 32) | (ull)kq0;
                const ull kb = ((ull)__float_as_uint(d2[u].y) << 32) | (ull)kq1;
                bk = umax64(bk, umax64(ka, kb));
            }
            EXTRACT_RECORD();                          // refresh record (SGPRs)
        }
        if (lane == 0) {
            s_rec[1 - par][wv] = ((ull)my_khi << 32) | (ull)my_klo;
            s_recz[1 - par][wv] = my_qz;
        }
    }

    // final flush: picks 3584..4095 (ring half b=512) + n_o scalar
    __syncthreads();
    {
        const int base3 = 3584 * 3;
        const int b3 = 512 * 3;
        out[base3 + t] = s_pick[b3 + t];
        if (t < 512) out[base3 + 1024 + t] = s_pick[b3 + 1024 + t];
        if (t == 0) out[12288 + 786432] = 4096.0f;
    }
}

// ---------------------------------------------------------------------------
// Kernel 2 (R25): fused knn + vn. knn unchanged (bit-exactness). vn k-split
// as R16 with float4 staging (neutral measured, kept).
// ---------------------------------------------------------------------------
__global__ __launch_bounds__(1024)
void knnvn_kernel(const float* __restrict__ p, const float* __restrict__ x,
                  const float* __restrict__ Wf, const float* __restrict__ Wd,
                  float* __restrict__ out) {
    __shared__ __align__(16) char SMEM[133120];
    float* sWf = (float*)SMEM;                         // 16 KB  [c*64+o]
    float* sWd = (float*)(SMEM + 16384);               // 16 KB
    float* sg  = (float*)(SMEM + 32768);               // 96 KB  16 q x 8 k x 192
    int*  s_nn = (int*)(SMEM + 131072);                // 1 KB   16 q x 16

    const int t = threadIdx.x;
    const int lane = t & 63, wv = t >> 6;
    const int qbase = (int)blockIdx.x * 16;            // 256 blocks x 16 = 4096

    for (int u = t; u < CIN * COUT; u += 1024) {
        const int o = u >> 6, c = u & 63;
        sWf[c * 64 + o] = Wf[u];
        sWd[c * 64 + o] = Wd[u];
    }

    // ---- knn: one wave per query, results into LDS (exact top_k semantics) ----
    {
        const int m = qbase + wv;
        const float qx = out[3 * m], qy = out[3 * m + 1], qz = out[3 * m + 2];
        const float qq2 = __fadd_rn(__fadd_rn(__fmul_rn(qx, qx), __fmul_rn(qy, qy)),
                                    __fmul_rn(qz, qz));
        float D[16]; int I[16];
#pragma unroll
        for (int s = 0; s < 16; ++s) { D[s] = FLT_MAX; I[s] = 0x7fffffff; }
        for (int c = 0; c < N_PTS / 64; ++c) {
            const int j = c * 64 + lane;
            const float px = p[3 * j], py = p[3 * j + 1], pz = p[3 * j + 2];
            const float pp = __fadd_rn(__fadd_rn(__fmul_rn(px, px), __fmul_rn(py, py)),
                                       __fmul_rn(pz, pz));
            const float qp = __fadd_rn(__fadd_rn(__fmul_rn(qx, px), __fmul_rn(qy, py)),
                                       __fmul_rn(qz, pz));
            const float d = __fadd_rn(__fsub_rn(qq2, __fmul_rn(2.0f, qp)), pp);
            if (d < D[15]) {
                D[15] = d; I[15] = j;
#pragma unroll
                for (int s = 15; s > 0; --s) {
                    if (D[s] < D[s - 1]) {
                        float tf = D[s]; D[s] = D[s - 1]; D[s - 1] = tf;
                        int   ti = I[s]; I[s] = I[s - 1]; I[s - 1] = ti;
                    }
                }
            }
        }
        int myout = 0;
        for (int r = 0; r < 16; ++r) {
            float v = D[0]; int ix = I[0]; int bl = lane;
#pragma unroll
            for (int off = 1; off < 64; off <<= 1) {
                float ov = __shfl_xor(v, off);
                int   oi = __shfl_xor(ix, off);
                int   ol = __shfl_xor(bl, off);
                if (ov < v || (ov == v && oi < ix)) { v = ov; ix = oi; bl = ol; }
            }
            if (lane == bl) {
#pragma unroll
                for (int s = 0; s < 15; ++s) { D[s] = D[s + 1]; I[s] = I[s + 1]; }
                D[15] = FLT_MAX; I[15] = 0x7fffffff;
            }
            if (lane == r) myout = ix;
        }
        if (lane < K_NN) s_nn[wv * K_NN + lane] = myout;
    }

    // ---- vn, k-split: all 1024 threads = (qi 0..15, o 0..63) ----
    const int qi = t >> 6, o = t & 63;
    float a0 = 0.0f, a1 = 0.0f, a2 = 0.0f;
#pragma unroll
    for (int half = 0; half < 2; ++half) {
        __syncthreads();                               // nn ready / sg reuse safe
        // stage k in [half*8, half*8+8) for all 16 queries: 6144 float4s
        for (int idx4 = t; idx4 < 16 * 8 * 48; idx4 += 1024) {
            const int pair = idx4 / 48;                // qj*8 + kk
            const int c4 = idx4 - pair * 48;
            const int jn = s_nn[(pair >> 3) * K_NN + half * 8 + (pair & 7)];
            *(float4*)&sg[pair * 192 + c4 * 4] =
                *(const float4*)&x[jn * 192 + c4 * 4];
        }
        __syncthreads();
        for (int kk = 0; kk < 8; ++kk) {
            const float* gk = &sg[(qi * 8 + kk) * 192];
            float q0 = 0.0f, q1 = 0.0f, q2 = 0.0f;
            float d0 = 0.0f, d1 = 0.0f, d2v = 0.0f;
#pragma unroll 8
            for (int c = 0; c < CIN; ++c) {
                const float wf = sWf[c * 64 + o];
                const float wd = sWd[c * 64 + o];
                const float g0 = gk[c * 3], g1 = gk[c * 3 + 1], g2 = gk[c * 3 + 2];
                q0 = fmaf(wf, g0, q0); q1 = fmaf(wf, g1, q1); q2 = fmaf(wf, g2, q2);
                d0 = fmaf(wd, g0, d0); d1 = fmaf(wd, g1, d1); d2v = fmaf(wd, g2, d2v);
            }
            const float dot = q0 * d0 + q1 * d1 + q2 * d2v;
            const float dns = d0 * d0 + d1 * d1 + d2v * d2v + 1e-6f;
            const float f = (dot >= 0.0f) ? 0.0f : 0.8f * (dot / dns);
            a0 += q0 - f * d0;
            a1 += q1 - f * d1;
            a2 += q2 - f * d2v;
        }
    }
    float* xo = out + 12288;
    const int m = qbase + qi;
    xo[(o * 3 + 0) * M_PTS + m] = a0 * 0.0625f;        // mean over 16
    xo[(o * 3 + 1) * M_PTS + m] = a1 * 0.0625f;
    xo[(o * 3 + 2) * M_PTS + m] = a2 * 0.0625f;
}

// ---------------------------------------------------------------------------
extern "C" void kernel_launch(void* const* d_in, const int* in_sizes, int n_in,
                              void* d_out, int out_size, void* d_ws, size_t ws_size,
                              hipStream_t stream) {
    const float* p  = (const float*)d_in[0];
    const float* x  = (const float*)d_in[1];
    const float* Wf = (const float*)d_in[2];
    const float* Wd = (const float*)d_in[3];
    float* out = (float*)d_out;

    fps_kernel<<<1, 1024, 0, stream>>>(p, out);
    knnvn_kernel<<<256, 1024, 0, stream>>>(p, x, Wf, Wd, out);
}

// Round 12
// 4516.903 us; speedup vs baseline: 1.1569x; 1.1569x over previous
//
#include <hip/hip_runtime.h>
#include <float.h>

#define N_PTS 16384
#define M_PTS 4096
#define K_NN  16
#define CIN   64
#define COUT  64

typedef float v2f __attribute__((ext_vector_type(2)));
typedef unsigned long long ull;

// Exact f32 rounding to match numpy/jax: ((dx*dx + dy*dy) + dz*dz), no fma contraction.
__device__ __forceinline__ float dist2_exact(float ax, float ay, float az,
                                             float bx, float by, float bz) {
    float dx = __fsub_rn(ax, bx);
    float dy = __fsub_rn(ay, by);
    float dz = __fsub_rn(az, bz);
    return __fadd_rn(__fadd_rn(__fmul_rn(dx, dx), __fmul_rn(dy, dy)), __fmul_rn(dz, dz));
}

// Packed f32 ops via inline asm (v2f codegen otherwise scalarizes — R6 evidence).
__device__ __forceinline__ v2f pk_add(v2f a, v2f b) {
    v2f d; asm("v_pk_add_f32 %0, %1, %2" : "=v"(d) : "v"(a), "v"(b)); return d;
}
__device__ __forceinline__ v2f pk_mul(v2f a, v2f b) {
    v2f d; asm("v_pk_mul_f32 %0, %1, %2" : "=v"(d) : "v"(a), "v"(b)); return d;
}

// ---- DPP wave-64 reduction step for packed u64 keys (idempotent max) ----
template <int CTRL>
__device__ __forceinline__ ull dpp_u64max_step(ull x) {
    int lo = (int)(unsigned)x;
    int hi = (int)(unsigned)(x >> 32);
    unsigned olo = (unsigned)__builtin_amdgcn_update_dpp(lo, lo, CTRL, 0xf, 0xf, false);
    unsigned ohi = (unsigned)__builtin_amdgcn_update_dpp(hi, hi, CTRL, 0xf, 0xf, false);
    ull o = ((ull)ohi << 32) | (ull)olo;
    return o > x ? o : x;
}
__device__ __forceinline__ ull umax64(ull a, ull b) { return a > b ? a : b; }

// Compile-time-indexed 8-way select (uniform _sh -> cndmask tree, no scratch).
#define SEL8(arr)                                                                 \
    ((_sh & 4) ? ((_sh & 2) ? ((_sh & 1) ? arr[7] : arr[6])                       \
                            : ((_sh & 1) ? arr[5] : arr[4]))                      \
               : ((_sh & 2) ? ((_sh & 1) ? arr[3] : arr[2])                       \
                            : ((_sh & 1) ? arr[1] : arr[0])))

// Per-wave record extraction (R21): key = d2_bits<<32 | ((orig^0x3fff)<<14 | sortpos).
// u64-max == (argmax d2, tie-break min orig) — bit-identical winner selection to
// R1 (orig is unique and fits 14 bits, so sortpos never decides). sortpos encodes
// the owning thread, so NO ballot/ctz: candidate z comes from the owner lane's zp
// regs ((klo>>4)&63 within this wave) via uniform cndmask tree + one readlane.
#define EXTRACT_RECORD()                                                          \
    {                                                                             \
        ull _r = bk;                                                              \
        _r = dpp_u64max_step<0x111>(_r);                                          \
        _r = dpp_u64max_step<0x112>(_r);                                          \
        _r = dpp_u64max_step<0x114>(_r);                                          \
        _r = dpp_u64max_step<0x118>(_r);                                          \
        _r = dpp_u64max_step<0x142>(_r);                                          \
        _r = dpp_u64max_step<0x143>(_r);                                          \
        my_klo = (unsigned)__builtin_amdgcn_readlane((int)(unsigned)_r, 63);      \
        my_khi = (unsigned)__builtin_amdgcn_readlane((int)(unsigned)(_r >> 32), 63); \
        my_wval = __int_as_float((int)my_khi);                                    \
        const int _hl = (int)((my_klo >> 4) & 63u);    /* owner lane (own wave) */ \
        const int _slot = (int)(my_klo & 15u);                                    \
        const int _sh = _slot >> 1;                                              \
        v2f _za = SEL8(zp);                                                       \
        const float _zc = (_slot & 1) ? _za.y : _za.x;                            \
        my_qz = __int_as_float(__builtin_amdgcn_readlane(__float_as_int(_zc), _hl)); \
    }

// ---------------------------------------------------------------------------
// Kernel 1: furthest point sampling — R21 VERBATIM (best measured: 4217 µs,
// Rounds 5/9). Failed variants, for the record: R22 single-reducer (neutral),
// R24 payload reduce (+1.3 ms, VGPR cap + issue), R26 Morton/AABB prune
// (+640 µs, no active-wave reduction). fps internals are plateaued here.
// Register budget <64 by design (R2/R3: allocator caps at 64, spills past).
// ---------------------------------------------------------------------------
__global__ __launch_bounds__(1024) void fps_kernel(const float* __restrict__ p,
                                                   float* __restrict__ out) {
#pragma clang fp contract(off)
    const int t = threadIdx.x;
    const int lane = t & 63, wv = t >> 6;
    __shared__ char smem[147456];                      // keys[16384] then s_xy4[1024*9]
    __shared__ float s_pick[1024 * 3];                 // pick ring (12 KB)
    __shared__ ull s_rec[2][16];                       // bare u64 records
    __shared__ float s_recz[2][16];                    // winner-candidate z per wave

    ull* keys = (ull*)smem;
    float4* s_xy4 = (float4*)smem;                     // reuses keys region (144 KB)

    // ---- Phase A: bitonic sort by x (keys unique via idx bits) ----
    for (int u = 0; u < 16; ++u) {
        const int j = u * 1024 + t;
        keys[j] = ((ull)__float_as_uint(p[3 * j]) << 32) | (unsigned)j;
    }
    __syncthreads();
    for (int k = 2; k <= N_PTS; k <<= 1) {
        for (int j = k >> 1; j > 0; j >>= 1) {
            for (int e = 0; e < 8; ++e) {
                const int c = e * 1024 + t;
                const int i1 = 2 * c - (c & (j - 1));
                const int i2 = i1 + j;
                const ull a = keys[i1], b = keys[i2];
                const bool up = ((i1 & k) == 0);
                if ((a > b) == up) { keys[i1] = b; keys[i2] = a; }
            }
            __syncthreads();
        }
    }

    // read own 16 sorted keys -> packed original indices (8 regs)
    unsigned opk[8];
#pragma unroll
    for (int u = 0; u < 8; ++u) {
        const ull a = keys[t * 16 + 2 * u];
        const ull b = keys[t * 16 + 2 * u + 1];
        opk[u] = ((unsigned)a & 0xffffu) | (((unsigned)b & 0xffffu) << 16);
    }
    __syncthreads();                                   // all key reads done before overwrite

    // ---- gather coords: LDS xy ({x0,x1,y0,y1}) + reg z/d2, init bk ----
    v2f zp[8], d2[8];
    unsigned kqx[8], kqy[8];                           // (orig^0x3fff)<<14 | sortpos
    const float q0x = p[0], q0y = p[1], q0z = p[2];
    ull bk = 0;
    float xf = 0.0f, xl = 0.0f;
#pragma unroll
    for (int u = 0; u < 8; ++u) {
        const int o0 = (int)(opk[u] & 0xffffu), o1 = (int)(opk[u] >> 16);
        const float x0 = p[3 * o0], y0 = p[3 * o0 + 1], z0 = p[3 * o0 + 2];
        const float x1 = p[3 * o1], y1 = p[3 * o1 + 1], z1 = p[3 * o1 + 2];
        s_xy4[t * 9 + u] = make_float4(x0, x1, y0, y1);
        zp[u] = (v2f){z0, z1};
        d2[u] = (v2f){dist2_exact(x0, y0, z0, q0x, q0y, q0z),
                      dist2_exact(x1, y1, z1, q0x, q0y, q0z)};
        kqx[u] = ((unsigned)(o0 ^ 0x3fff) << 14) | (unsigned)(t * 16 + 2 * u);
        kqy[u] = ((unsigned)(o1 ^ 0x3fff) << 14) | (unsigned)(t * 16 + 2 * u + 1);
        const ull ka = ((ull)__float_as_uint(d2[u].x) << 32) | (ull)kqx[u];
        const ull kb = ((ull)__float_as_uint(d2[u].y) << 32) | (ull)kqy[u];
        bk = umax64(bk, umax64(ka, kb));
        if (u == 0) xf = x0;
        if (u == 7) xl = x1;
    }
    const float wxmin = __int_as_float(__builtin_amdgcn_readlane(__float_as_int(xf), 0));
    const float wxmax = __int_as_float(__builtin_amdgcn_readlane(__float_as_int(xl), 63));
    const float cx = 0.5f * (wxmin + wxmax);
    const float hw_safe = 0.5f * (wxmax - wxmin) + 1e-5f;

    float my_wval, my_qz;
    unsigned my_klo, my_khi;
    EXTRACT_RECORD();
    if (lane == 0) {
        s_rec[1][wv] = ((ull)my_khi << 32) | (ull)my_klo;
        s_recz[1][wv] = my_qz;
    }
    if (t == 0) { s_pick[0] = q0x; s_pick[1] = q0y; s_pick[2] = q0z; }

    for (int i = 1; i < M_PTS; ++i) {
        const int par = i & 1;
        __syncthreads();                               // the ONE barrier per iteration

        // ring flush: once per 512 iters, previous 512-block (other ring half)
        if ((i & 511) == 0) {
            const int b = (i - 512) & 1023;
            const int base3 = (i - 512) * 3;
            out[base3 + t] = s_pick[b * 3 + t];
            if (t < 512) out[base3 + 1024 + t] = s_pick[b * 3 + 1024 + t];
        }

        // global winner from the 16 records, then uniform broadcast coord fetch
        const int r = lane & 15;
        ull red = s_rec[par][r];
        red = dpp_u64max_step<0x111>(red);
        red = dpp_u64max_step<0x112>(red);
        red = dpp_u64max_step<0x114>(red);
        red = dpp_u64max_step<0x118>(red);
        const unsigned wlo = (unsigned)__builtin_amdgcn_readlane((int)(unsigned)red, 63);
        const unsigned sortpos = wlo & 0x3fffu;
        const int to = (int)(sortpos >> 4), slot = (int)(sortpos & 15u);
        const float qz = s_recz[par][sortpos >> 10];   // record idx = owning wave
        const float4 xy = s_xy4[to * 9 + (slot >> 1)]; // uniform addr -> broadcast
        const float qx = (slot & 1) ? xy.y : xy.x;
        const float qy = (slot & 1) ? xy.w : xy.z;
        if (t == 0) {
            const int s3 = (i & 1023) * 3;
            s_pick[s3] = qx; s_pick[s3 + 1] = qy; s_pick[s3 + 2] = qz;
        }

        // ---- wave-level slab prune: skip update iff provably all no-ops ----
        const float dxq = fabsf(qx - cx);
        bool active = true;
        if (dxq > hw_safe) {
            const float lb = dxq - hw_safe;            // conservative lower bound
            active = (lb * lb <= my_wval);
        }
        if (active) {
            const v2f nqx2 = (v2f){-qx, -qx};
            const v2f nqy2 = (v2f){-qy, -qy};
            const v2f nqz2 = (v2f){-qz, -qz};
            bk = 0;
#pragma unroll
            for (int u = 0; u < 8; ++u) {
                const float4 xyu = s_xy4[t * 9 + u];
                const v2f xp = (v2f){xyu.x, xyu.y};    // {x0,x1}
                const v2f yp = (v2f){xyu.z, xyu.w};    // {y0,y1}
                const v2f dx = pk_add(xp, nqx2);       // exact x - qx
                const v2f dy = pk_add(yp, nqy2);
                const v2f dz = pk_add(zp[u], nqz2);
                const v2f m1 = pk_mul(dx, dx);
                const v2f m2 = pk_mul(dy, dy);
                const v2f m3 = pk_mul(dz, dz);
                const v2f s = pk_add(pk_add(m1, m2), m3);  // ((x²+y²)+z²) exact order
                d2[u] = __builtin_elementwise_min(d2[u], s);
                const ull ka = ((ull)__float_as_uint(d2[u].x) << 32) | (ull)kqx[u];
                const ull kb = ((ull)__float_as_uint(d2[u].y) << 32) | (ull)kqy[u];
                bk = umax64(bk, umax64(ka, kb));
            }
            EXTRACT_RECORD();                          // refresh record (SGPRs)
        }
        if (lane == 0) {
            s_rec[1 - par][wv] = ((ull)my_khi << 32) | (ull)my_klo;
            s_recz[1 - par][wv] = my_qz;
        }
    }

    // final flush: picks 3584..4095 (ring half b=512) + n_o scalar
    __syncthreads();
    {
        const int base3 = 3584 * 3;
        const int b3 = 512 * 3;
        out[base3 + t] = s_pick[b3 + t];
        if (t < 512) out[base3 + 1024 + t] = s_pick[b3 + 1024 + t];
        if (t == 0) out[12288 + 786432] = 4096.0f;
    }
}

// ---------------------------------------------------------------------------
// Kernel 2 (R27): fused knn + vn. knn + staging unchanged (R25). vn compute
// loop restructured to cut LDS-pipe pressure (measured gap: ~23k instr/wave
// issue model = ~77 µs vs 355 µs measured -> LDS serialization dominates):
//  - gk reads: 3 uniform ds_read_b128 per (kk, 4-c group) replacing 12 b32
//    (rows are 768 B-aligned; 48 B groups stay 16 B-aligned)
//  - wf/wd hoisted over a kk-tile of 4: read once per c per tile (2048->512)
// Accumulation order per kk (c ascending) and kk order 0..15 unchanged.
// ---------------------------------------------------------------------------
__global__ __launch_bounds__(1024)
void knnvn_kernel(const float* __restrict__ p, const float* __restrict__ x,
                  const float* __restrict__ Wf, const float* __restrict__ Wd,
                  float* __restrict__ out) {
    __shared__ __align__(16) char SMEM[133120];
    float* sWf = (float*)SMEM;                         // 16 KB  [c*64+o]
    float* sWd = (float*)(SMEM + 16384);               // 16 KB
    float* sg  = (float*)(SMEM + 32768);               // 96 KB  16 q x 8 k x 192
    int*  s_nn = (int*)(SMEM + 131072);                // 1 KB   16 q x 16

    const int t = threadIdx.x;
    const int lane = t & 63, wv = t >> 6;
    const int qbase = (int)blockIdx.x * 16;            // 256 blocks x 16 = 4096

    for (int u = t; u < CIN * COUT; u += 1024) {
        const int o = u >> 6, c = u & 63;
        sWf[c * 64 + o] = Wf[u];
        sWd[c * 64 + o] = Wd[u];
    }

    // ---- knn: one wave per query, results into LDS (exact top_k semantics) ----
    {
        const int m = qbase + wv;
        const float qx = out[3 * m], qy = out[3 * m + 1], qz = out[3 * m + 2];
        const float qq2 = __fadd_rn(__fadd_rn(__fmul_rn(qx, qx), __fmul_rn(qy, qy)),
                                    __fmul_rn(qz, qz));
        float D[16]; int I[16];
#pragma unroll
        for (int s = 0; s < 16; ++s) { D[s] = FLT_MAX; I[s] = 0x7fffffff; }
        for (int c = 0; c < N_PTS / 64; ++c) {
            const int j = c * 64 + lane;
            const float px = p[3 * j], py = p[3 * j + 1], pz = p[3 * j + 2];
            const float pp = __fadd_rn(__fadd_rn(__fmul_rn(px, px), __fmul_rn(py, py)),
                                       __fmul_rn(pz, pz));
            const float qp = __fadd_rn(__fadd_rn(__fmul_rn(qx, px), __fmul_rn(qy, py)),
                                       __fmul_rn(qz, pz));
            const float d = __fadd_rn(__fsub_rn(qq2, __fmul_rn(2.0f, qp)), pp);
            if (d < D[15]) {
                D[15] = d; I[15] = j;
#pragma unroll
                for (int s = 15; s > 0; --s) {
                    if (D[s] < D[s - 1]) {
                        float tf = D[s]; D[s] = D[s - 1]; D[s - 1] = tf;
                        int   ti = I[s]; I[s] = I[s - 1]; I[s - 1] = ti;
                    }
                }
            }
        }
        int myout = 0;
        for (int r = 0; r < 16; ++r) {
            float v = D[0]; int ix = I[0]; int bl = lane;
#pragma unroll
            for (int off = 1; off < 64; off <<= 1) {
                float ov = __shfl_xor(v, off);
                int   oi = __shfl_xor(ix, off);
                int   ol = __shfl_xor(bl, off);
                if (ov < v || (ov == v && oi < ix)) { v = ov; ix = oi; bl = ol; }
            }
            if (lane == bl) {
#pragma unroll
                for (int s = 0; s < 15; ++s) { D[s] = D[s + 1]; I[s] = I[s + 1]; }
                D[15] = FLT_MAX; I[15] = 0x7fffffff;
            }
            if (lane == r) myout = ix;
        }
        if (lane < K_NN) s_nn[wv * K_NN + lane] = myout;
    }

    // ---- vn, k-split: all 1024 threads = (qi 0..15, o 0..63) ----
    const int qi = t >> 6, o = t & 63;
    float a0 = 0.0f, a1 = 0.0f, a2 = 0.0f;
#pragma unroll
    for (int half = 0; half < 2; ++half) {
        __syncthreads();                               // nn ready / sg reuse safe
        // stage k in [half*8, half*8+8) for all 16 queries: 6144 float4s
        for (int idx4 = t; idx4 < 16 * 8 * 48; idx4 += 1024) {
            const int pair = idx4 / 48;                // qj*8 + kk
            const int c4 = idx4 - pair * 48;
            const int jn = s_nn[(pair >> 3) * K_NN + half * 8 + (pair & 7)];
            *(float4*)&sg[pair * 192 + c4 * 4] =
                *(const float4*)&x[jn * 192 + c4 * 4];
        }
        __syncthreads();
#pragma unroll
        for (int kt = 0; kt < 2; ++kt) {               // kk tile of 4
            const float* gbase = &sg[(qi * 8 + kt * 4) * 192];
            float qa[4][3] = {{0,0,0},{0,0,0},{0,0,0},{0,0,0}};
            float da[4][3] = {{0,0,0},{0,0,0},{0,0,0},{0,0,0}};
            for (int cg = 0; cg < 16; ++cg) {          // 4 c's per group
                const float wf0 = sWf[(cg * 4 + 0) * 64 + o];
                const float wf1 = sWf[(cg * 4 + 1) * 64 + o];
                const float wf2 = sWf[(cg * 4 + 2) * 64 + o];
                const float wf3 = sWf[(cg * 4 + 3) * 64 + o];
                const float wd0 = sWd[(cg * 4 + 0) * 64 + o];
                const float wd1 = sWd[(cg * 4 + 1) * 64 + o];
                const float wd2 = sWd[(cg * 4 + 2) * 64 + o];
                const float wd3 = sWd[(cg * 4 + 3) * 64 + o];
#pragma unroll
                for (int kk = 0; kk < 4; ++kk) {
                    const float* gk = gbase + kk * 192;
                    const float4 v0 = *(const float4*)&gk[cg * 12 + 0];
                    const float4 v1 = *(const float4*)&gk[cg * 12 + 4];
                    const float4 v2 = *(const float4*)&gk[cg * 12 + 8];
                    // c = 4cg+0: {v0.x v0.y v0.z}
                    qa[kk][0] = fmaf(wf0, v0.x, qa[kk][0]);
                    qa[kk][1] = fmaf(wf0, v0.y, qa[kk][1]);
                    qa[kk][2] = fmaf(wf0, v0.z, qa[kk][2]);
                    da[kk][0] = fmaf(wd0, v0.x, da[kk][0]);
                    da[kk][1] = fmaf(wd0, v0.y, da[kk][1]);
                    da[kk][2] = fmaf(wd0, v0.z, da[kk][2]);
                    // c = 4cg+1: {v0.w v1.x v1.y}
                    qa[kk][0] = fmaf(wf1, v0.w, qa[kk][0]);
                    qa[kk][1] = fmaf(wf1, v1.x, qa[kk][1]);
                    qa[kk][2] = fmaf(wf1, v1.y, qa[kk][2]);
                    da[kk][0] = fmaf(wd1, v0.w, da[kk][0]);
                    da[kk][1] = fmaf(wd1, v1.x, da[kk][1]);
                    da[kk][2] = fmaf(wd1, v1.y, da[kk][2]);
                    // c = 4cg+2: {v1.z v1.w v2.x}
                    qa[kk][0] = fmaf(wf2, v1.z, qa[kk][0]);
                    qa[kk][1] = fmaf(wf2, v1.w, qa[kk][1]);
                    qa[kk][2] = fmaf(wf2, v2.x, qa[kk][2]);
                    da[kk][0] = fmaf(wd2, v1.z, da[kk][0]);
                    da[kk][1] = fmaf(wd2, v1.w, da[kk][1]);
                    da[kk][2] = fmaf(wd2, v2.x, da[kk][2]);
                    // c = 4cg+3: {v2.y v2.z v2.w}
                    qa[kk][0] = fmaf(wf3, v2.y, qa[kk][0]);
                    qa[kk][1] = fmaf(wf3, v2.z, qa[kk][1]);
                    qa[kk][2] = fmaf(wf3, v2.w, qa[kk][2]);
                    da[kk][0] = fmaf(wd3, v2.y, da[kk][0]);
                    da[kk][1] = fmaf(wd3, v2.z, da[kk][1]);
                    da[kk][2] = fmaf(wd3, v2.w, da[kk][2]);
                }
            }
#pragma unroll
            for (int kk = 0; kk < 4; ++kk) {           // kk order 0..15 preserved
                const float dot = qa[kk][0] * da[kk][0] + qa[kk][1] * da[kk][1]
                                + qa[kk][2] * da[kk][2];
                const float dns = da[kk][0] * da[kk][0] + da[kk][1] * da[kk][1]
                                + da[kk][2] * da[kk][2] + 1e-6f;
                const float f = (dot >= 0.0f) ? 0.0f : 0.8f * (dot / dns);
                a0 += qa[kk][0] - f * da[kk][0];
                a1 += qa[kk][1] - f * da[kk][1];
                a2 += qa[kk][2] - f * da[kk][2];
            }
        }
    }
    float* xo = out + 12288;
    const int m = qbase + qi;
    xo[(o * 3 + 0) * M_PTS + m] = a0 * 0.0625f;        // mean over 16
    xo[(o * 3 + 1) * M_PTS + m] = a1 * 0.0625f;
    xo[(o * 3 + 2) * M_PTS + m] = a2 * 0.0625f;
}

// ---------------------------------------------------------------------------
extern "C" void kernel_launch(void* const* d_in, const int* in_sizes, int n_in,
                              void* d_out, int out_size, void* d_ws, size_t ws_size,
                              hipStream_t stream) {
    const float* p  = (const float*)d_in[0];
    const float* x  = (const float*)d_in[1];
    const float* Wf = (const float*)d_in[2];
    const float* Wd = (const float*)d_in[3];
    float* out = (float*)d_out;

    fps_kernel<<<1, 1024, 0, stream>>>(p, out);
    knnvn_kernel<<<256, 1024, 0, stream>>>(p, x, Wf, Wd, out);
}